// Round 21
// baseline (229.280 us; speedup 1.0000x reference)
//
#include <hip/hip_runtime.h>

#define FIN 128
#define HID 64
#define CLS 32

#define BSH 7            // bucket covers 128 nodes
#define BNODES 128
#define GB 256           // chunks / blocks in sort pass (CHUNK=6250 @ E=1.6M)
#define BCAP 4096        // max records per bucket staged in LDS (mean ~2046)
#define SCAP 6272        // >= CHUNK: per-block staging capacity
#define NBUKP 800        // padded per-block loffB stride (>= NBUK+1)

// dynamic-LDS layout for the fused first kernel
#define SM_STAGE 0                     // int2[SCAP]   = 50176 B
#define SM_LCNT  50176                 // int[NBUKP]*3 = 9600 B
#define SM_SSUM  (50176 + 9600)       // int[1024]    = 4096 B
#define SM_BYTES (50176 + 9600 + 4096) // 63872 (gemm path reuses first 32 KB)

// R20 FINAL: session-best configuration, measured 228.9/229.7/230.0us across
// three clean runs (absmax 9.77e-4, passed each). Trajectory 239.9 -> 228.9
// (-4.6%). Wins: pull_agg 2->4 unroll (R0, -5.3us), flattened coalesced
// k_bucket gather (R2, -4.9us). Falsified+reverted: dinv coef fold (R5,
// +9.2us), kernel split (R12, +4.4us — fused sort/gemm blocks load-balance).
// Neutral kept: wave-scan in sort path (R11). 8-deep unroll probe (R18)
// never measured due to infra; ILP ladder closed at measured depth 4.

using bfrag = __attribute__((ext_vector_type(8))) short;   // 8 bf16 (4 VGPRs)
using cfrag = __attribute__((ext_vector_type(4))) float;   // 4 fp32 acc

__device__ inline unsigned short f2bf(float x) {
  unsigned u = __float_as_uint(x);
  return (unsigned short)((u + 0x7FFFu + ((u >> 16) & 1u)) >> 16);
}
__device__ inline void bf8_to_f32(int4 v, float* f) {
  f[0] = __uint_as_float((unsigned)v.x << 16);
  f[1] = __uint_as_float((unsigned)v.x & 0xFFFF0000u);
  f[2] = __uint_as_float((unsigned)v.y << 16);
  f[3] = __uint_as_float((unsigned)v.y & 0xFFFF0000u);
  f[4] = __uint_as_float((unsigned)v.z << 16);
  f[5] = __uint_as_float((unsigned)v.z & 0xFFFF0000u);
  f[6] = __uint_as_float((unsigned)v.w << 16);
  f[7] = __uint_as_float((unsigned)v.w & 0xFFFF0000u);
}

// ---------------- fused first dispatch ----------------
// blocks [0,GB):       block-local counting sort of edge chunks
// block GB:            W2 pre-pack (B-frag order)
// blocks (GB, GB+NG]:  gemm1: xs1 = bf16(x @ W1)  (UNSCALED — dinv deferred to pull)
// Sort and gemm blocks co-resident: mutual latency hiding (R16 lesson).
__global__ __launch_bounds__(1024) void k_sort_gemm(const int* __restrict__ src,
                                                    const int* __restrict__ dst,
                                                    const float* __restrict__ ew,
                                                    int2* __restrict__ recsA,
                                                    int* __restrict__ gcntT,
                                                    int* __restrict__ loffB,
                                                    const float* __restrict__ W1,
                                                    const float* __restrict__ W2,
                                                    unsigned short* __restrict__ wp2,
                                                    const float* __restrict__ x,
                                                    unsigned short* __restrict__ xs1,
                                                    int E, int CHUNK, int NBUK, int N) {
  extern __shared__ char sm[];
  const int b = blockIdx.x, t = threadIdx.x;

  if (b == GB) {  // ---- W2 pack ----
    for (int i = t; i < 4 * 512; i += 1024) {
      int f = i >> 9, l = (i >> 3) & 63, j = i & 7;
      int ks = f >> 1, nt = f & 1;
      int k = ks * 32 + (l >> 4) * 8 + j;
      int n = nt * 16 + (l & 15);
      wp2[i] = f2bf(W2[k * 32 + n]);
    }
    return;
  }

  if (b > GB) {  // ---- gemm1 blocks: 256 rows each (16 waves x 16-row tiles) ----
    float* w1s = (float*)sm;  // 32 KB
    for (int i = t; i < FIN * HID; i += 1024) w1s[i] = W1[i];
    __syncthreads();
    const int lane = t & 63;
    const int quad = lane >> 4;
    const int col = lane & 15;
    const int row0 = (b - GB - 1) * 256 + (t >> 6) * 16;
    if (row0 >= N) return;

    bfrag bf[16];
#pragma unroll
    for (int ks = 0; ks < 4; ++ks)
#pragma unroll
      for (int nt = 0; nt < 4; ++nt) {
        bfrag v;
#pragma unroll
        for (int j = 0; j < 8; ++j)
          v[j] = (short)f2bf(w1s[(ks * 32 + quad * 8 + j) * HID + nt * 16 + col]);
        bf[ks * 4 + nt] = v;
      }

    cfrag acc[4] = {};
    int row_a = row0 + col;
    if (row_a >= N) row_a = N - 1;
    const float* xp = x + (size_t)row_a * FIN + quad * 8;

#pragma unroll
    for (int ks = 0; ks < 4; ++ks) {
      float4 a0 = *(const float4*)(xp + ks * 32);
      float4 a1 = *(const float4*)(xp + ks * 32 + 4);
      bfrag af;
      af[0] = (short)f2bf(a0.x); af[1] = (short)f2bf(a0.y);
      af[2] = (short)f2bf(a0.z); af[3] = (short)f2bf(a0.w);
      af[4] = (short)f2bf(a1.x); af[5] = (short)f2bf(a1.y);
      af[6] = (short)f2bf(a1.z); af[7] = (short)f2bf(a1.w);
#pragma unroll
      for (int nt = 0; nt < 4; ++nt)
        acc[nt] = __builtin_amdgcn_mfma_f32_16x16x32_bf16(af, bf[ks * 4 + nt], acc[nt], 0, 0, 0);
    }
#pragma unroll
    for (int nt = 0; nt < 4; ++nt)
#pragma unroll
      for (int r = 0; r < 4; ++r) {
        int row = row0 + quad * 4 + r;
        if (row < N)
          xs1[(size_t)row * HID + nt * 16 + col] = f2bf(acc[nt][r]);
      }
    return;
  }

  // ---- sort blocks ----
  int2* stage = (int2*)(sm + SM_STAGE);
  int* lcnt = (int*)(sm + SM_LCNT);
  int* loff = lcnt + NBUKP;
  int* lcur = loff + NBUKP;
  int* ssum = (int*)(sm + SM_SSUM);

  const int s = b * CHUNK, e = min(E, s + CHUNK);
  const int m = e - s;

  for (int i = t; i < NBUK; i += 1024) lcnt[i] = 0;
  __syncthreads();
  for (int p = s + t; p < e; p += 1024)
    atomicAdd(&lcnt[dst[p] >> BSH], 1);
  __syncthreads();

  // R11 scan: per-wave __shfl_up + thread-0 serial scan of 16 wave totals.
  int c = (t < NBUK) ? lcnt[t] : 0;
  int incl = c;
#pragma unroll
  for (int off = 1; off < 64; off <<= 1) {
    int v = __shfl_up(incl, off, 64);
    if ((t & 63) >= off) incl += v;
  }
  if ((t & 63) == 63) ssum[t >> 6] = incl;   // 16 wave totals
  __syncthreads();
  if (t == 0) {
    int run = 0;
#pragma unroll
    for (int w = 0; w < 16; ++w) {
      int v = ssum[w];
      ssum[16 + w] = run;                    // exclusive wave offset
      run += v;
    }
  }
  __syncthreads();
  incl += ssum[16 + (t >> 6)];

  if (t < NBUK) { loff[t] = incl - c; lcur[t] = incl - c; }
  if (t == 0) loff[NBUK] = m;
  __syncthreads();

  for (int p = s + t; p < e; p += 1024) {
    int d = dst[p];
    int bk = d >> BSH;
    int pos = atomicAdd(&lcur[bk], 1);
    stage[pos] = make_int2(src[p] | ((d & (BNODES - 1)) << 17), __float_as_int(ew[p]));
  }
  __syncthreads();

  for (int p = t; p < m; p += 1024) recsA[s + p] = stage[p];
  for (int i = t; i < NBUK; i += 1024) gcntT[i * GB + b] = lcnt[i];
  for (int i = t; i <= NBUK; i += 1024) loffB[b * NBUKP + i] = loff[i];
}

// ---------------- 2-level exclusive scan (chunk = 4096, <=256 chunks) ----------------
__global__ __launch_bounds__(256) void k_scan_sums(const int* __restrict__ counts,
                                                   int* __restrict__ bsum, int N) {
  __shared__ int s[256];
  int base = blockIdx.x * 4096 + threadIdx.x * 16;
  int t = 0;
#pragma unroll
  for (int j = 0; j < 16; ++j)
    if (base + j < N) t += counts[base + j];
  s[threadIdx.x] = t;
  __syncthreads();
  for (int off = 128; off > 0; off >>= 1) {
    if (threadIdx.x < off) s[threadIdx.x] += s[threadIdx.x + off];
    __syncthreads();
  }
  if (threadIdx.x == 0) bsum[blockIdx.x] = s[0];
}

// in-place safe; each block redundantly scans bsum[0..nb) in LDS (nb <= 256)
__global__ __launch_bounds__(256) void k_scan_emit(const int* __restrict__ counts,
                                                   const int* __restrict__ bsum,
                                                   int* __restrict__ rowstart, int N, int nb) {
  __shared__ int sb[256];
  __shared__ int s[256];
  const int t = threadIdx.x;
  int bv = (t < nb) ? bsum[t] : 0;
  sb[t] = bv;
  __syncthreads();
  for (int off = 1; off < 256; off <<= 1) {
    int u = (t >= off) ? sb[t - off] : 0;
    __syncthreads();
    sb[t] += u;
    __syncthreads();
  }
  sb[t] -= bv;  // exclusive
  __syncthreads();
  const int bbase = sb[blockIdx.x];

  int base = blockIdx.x * 4096 + t * 16;
  int c[16];
  int tsum = 0;
#pragma unroll
  for (int j = 0; j < 16; ++j) {
    c[j] = (base + j < N) ? counts[base + j] : 0;
    tsum += c[j];
  }
  s[t] = tsum;
  __syncthreads();
  for (int off = 1; off < 256; off <<= 1) {
    int v = (t >= off) ? s[t - off] : 0;
    __syncthreads();
    s[t] += v;
    __syncthreads();
  }
  int run = bbase + s[t] - tsum;  // exclusive
#pragma unroll
  for (int j = 0; j < 16; ++j) {
    if (base + j < N) rowstart[base + j] = run;
    run += c[j];
  }
}

// ---------------- per-bucket finalize: node-ordered pairs via global scan ----------------
// R2 (measured -4.9us): flattened coalesced gather via run-start table +
// 8-step LDS binary search; consecutive p -> consecutive recsA addresses.
__global__ __launch_bounds__(256) void k_bucket(const int2* __restrict__ recsA,
                                                const int* __restrict__ goff,
                                                const int* __restrict__ loffB,
                                                int2* __restrict__ pairs,
                                                float* __restrict__ dinv,
                                                int* __restrict__ rowstart,
                                                int N, int E, int CHUNK, int NBUK) {
  __shared__ int2 lrec[BCAP];
  __shared__ int2 sout[BCAP];
  __shared__ int cnt[BNODES];
  __shared__ int cur[BNODES];
  __shared__ int sbuf[BNODES];
  __shared__ float degs[BNODES];
  __shared__ float dl[BNODES];
  __shared__ int rs[GB + 1];    // flattened run starts (monotone)
  __shared__ int ibase[GB];     // recsA index base per run: addr = ibase[r] + p
  const int b = blockIdx.x;
  const int t = threadIdx.x;
  const int bstart = goff[b * GB];
  const int bend = (b + 1 < NBUK) ? goff[(b + 1) * GB] : E;
  int m = bend - bstart;
  if (m > BCAP) m = BCAP;

  if (t < BNODES) { cnt[t] = 0; degs[t] = 1.0f; }  // self-loop weight
  // build run table (all 256 threads; GB == blockDim)
  {
    int ls = loffB[t * NBUKP + b];
    int doff = goff[b * GB + t] - bstart;
    rs[t] = doff;
    ibase[t] = t * CHUNK + ls - doff;
  }
  if (t == 0) rs[GB] = m;
  __syncthreads();

  // flattened gather: consecutive p -> consecutive recsA addresses within runs
  for (int p = t; p < m; p += 256) {
    int lo = 0;
#pragma unroll
    for (int step = 128; step > 0; step >>= 1) {
      int mid = lo + step;
      if (mid <= GB - 1 && rs[mid] <= p) lo = mid;
    }
    lrec[p] = recsA[ibase[lo] + p];
  }
  __syncthreads();

  for (int p = t; p < m; p += 256) {
    int2 r = lrec[p];
    int d = (r.x >> 17) & (BNODES - 1);
    atomicAdd(&cnt[d], 1);
    atomicAdd(&degs[d], __int_as_float(r.y));
  }
  __syncthreads();
  if (t < BNODES) sbuf[t] = cnt[t];
  __syncthreads();
  for (int off = 1; off < BNODES; off <<= 1) {
    int v = (t < BNODES && t >= off) ? sbuf[t - off] : 0;
    __syncthreads();
    if (t < BNODES) sbuf[t] += v;
    __syncthreads();
  }
  if (t < BNODES) {
    int ls = sbuf[t] - cnt[t];
    cur[t] = ls;
    float di = rsqrtf(degs[t]);
    dl[t] = di;
    int node = b * BNODES + t;
    if (node < N) { dinv[node] = di; rowstart[node] = bstart + ls; }
  }
  __syncthreads();
  for (int p = t; p < m; p += 256) {
    int2 r = lrec[p];
    int d = (r.x >> 17) & (BNODES - 1);
    int pos = atomicAdd(&cur[d], 1);
    float c = __int_as_float(r.y) * dl[d];  // ew * dinv[dst]
    sout[pos] = make_int2(r.x & 0x1FFFF, __float_as_int(c));
  }
  __syncthreads();
  for (int p = t; p < m; p += 256) pairs[bstart + p] = sout[p];
}

// ---------------- MFMA dense transform (layer 2): xs2 = bf16(dinv * (out1b @ W2)) ----------------
template <int K, int F>
__global__ __launch_bounds__(256, 4) void mfma_gemm2(const unsigned short* __restrict__ xv,
                                                     const unsigned short* __restrict__ wp,
                                                     const float* __restrict__ scale,
                                                     unsigned short* __restrict__ y, int N) {
  constexpr int KS = K / 32;
  constexpr int NT = F / 16;
  const int lane = threadIdx.x & 63;
  const int quad = lane >> 4;
  const int col = lane & 15;
  const int row0 = blockIdx.x * 64 + (threadIdx.x >> 6) * 16;
  if (row0 >= N) return;

  bfrag bf[KS * NT];
#pragma unroll
  for (int f = 0; f < KS * NT; ++f)
    bf[f] = *(const bfrag*)(wp + f * 512 + lane * 8);

  cfrag acc[NT] = {};
  int row_a = row0 + col;
  if (row_a >= N) row_a = N - 1;
  const unsigned short* xp = xv + (size_t)row_a * K + quad * 8;

#pragma unroll
  for (int ks = 0; ks < KS; ++ks) {
    bfrag af = *(const bfrag*)(xp + ks * 32);
#pragma unroll
    for (int nt = 0; nt < NT; ++nt)
      acc[nt] = __builtin_amdgcn_mfma_f32_16x16x32_bf16(af, bf[ks * NT + nt], acc[nt], 0, 0, 0);
  }

  float scr[4];
#pragma unroll
  for (int r = 0; r < 4; ++r) {
    int row = row0 + quad * 4 + r;
    scr[r] = (row < N) ? scale[row] : 0.f;
  }
#pragma unroll
  for (int nt = 0; nt < NT; ++nt)
#pragma unroll
    for (int r = 0; r < 4; ++r) {
      int row = row0 + quad * 4 + r;
      if (row < N)
        y[(size_t)row * F + nt * 16 + col] = f2bf(scr[r] * acc[nt][r]);
    }
}

// ---------------- pull aggregation ----------------
// DG=true  (layer 1): xs unscaled; out = b + di^2*xs[g] + sum coef*dinv[src]*xs[src]
// DG=false (layer 2): xs prescaled; out = b + di*xs[g] + sum coef*xs[src]
// R0 (measured -5.3us): 2->4 deep unroll for memory-pipeline depth.
template <int F, bool BF16OUT, bool DG>
__global__ __launch_bounds__(256) void pull_agg(const unsigned short* __restrict__ xs,
                                                const int2* __restrict__ pairs,
                                                const int* __restrict__ rowstart,
                                                const float* __restrict__ dinv,
                                                const float* __restrict__ b,
                                                void* __restrict__ outv, int N, int E) {
  constexpr int LPN = F / 8;        // lanes per node (8 features each, 16B loads)
  constexpr int NPB = 256 / LPN;
  const int g = blockIdx.x * NPB + threadIdx.x / LPN;
  const int f8 = (threadIdx.x % LPN) * 8;
  if (g >= N) return;

  const int start = rowstart[g];
  const int end = (g + 1 < N) ? rowstart[g + 1] : E;
  const float di = dinv[g];
  const float selfc = DG ? di * di : di;

  float acc[8];
  {
    int4 v = *(const int4*)&xs[(size_t)g * F + f8];
    float xf[8];
    bf8_to_f32(v, xf);
    float4 b0 = *(const float4*)&b[f8];
    float4 b1 = *(const float4*)&b[f8 + 4];
    acc[0] = fmaf(selfc, xf[0], b0.x); acc[1] = fmaf(selfc, xf[1], b0.y);
    acc[2] = fmaf(selfc, xf[2], b0.z); acc[3] = fmaf(selfc, xf[3], b0.w);
    acc[4] = fmaf(selfc, xf[4], b1.x); acc[5] = fmaf(selfc, xf[5], b1.y);
    acc[6] = fmaf(selfc, xf[6], b1.z); acc[7] = fmaf(selfc, xf[7], b1.w);
  }

  int p = start;
  for (; p + 4 <= end; p += 4) {
    int2 e0 = pairs[p];
    int2 e1 = pairs[p + 1];
    int2 e2 = pairs[p + 2];
    int2 e3 = pairs[p + 3];
    int4 v0 = *(const int4*)&xs[(size_t)e0.x * F + f8];
    int4 v1 = *(const int4*)&xs[(size_t)e1.x * F + f8];
    int4 v2 = *(const int4*)&xs[(size_t)e2.x * F + f8];
    int4 v3 = *(const int4*)&xs[(size_t)e3.x * F + f8];
    float c0 = __int_as_float(e0.y), c1 = __int_as_float(e1.y);
    float c2 = __int_as_float(e2.y), c3 = __int_as_float(e3.y);
    if (DG) {
      c0 *= dinv[e0.x]; c1 *= dinv[e1.x];
      c2 *= dinv[e2.x]; c3 *= dinv[e3.x];
    }
    float x0[8], x1[8], x2[8], x3[8];
    bf8_to_f32(v0, x0);
    bf8_to_f32(v1, x1);
    bf8_to_f32(v2, x2);
    bf8_to_f32(v3, x3);
#pragma unroll
    for (int j = 0; j < 8; ++j) acc[j] = fmaf(c0, x0[j], acc[j]);
#pragma unroll
    for (int j = 0; j < 8; ++j) acc[j] = fmaf(c1, x1[j], acc[j]);
#pragma unroll
    for (int j = 0; j < 8; ++j) acc[j] = fmaf(c2, x2[j], acc[j]);
#pragma unroll
    for (int j = 0; j < 8; ++j) acc[j] = fmaf(c3, x3[j], acc[j]);
  }
  for (; p + 2 <= end; p += 2) {
    int2 p0 = pairs[p];
    int2 p1 = pairs[p + 1];
    int4 v0 = *(const int4*)&xs[(size_t)p0.x * F + f8];
    int4 v1 = *(const int4*)&xs[(size_t)p1.x * F + f8];
    float c0 = __int_as_float(p0.y), c1 = __int_as_float(p1.y);
    if (DG) { c0 *= dinv[p0.x]; c1 *= dinv[p1.x]; }
    float x0[8], x1[8];
    bf8_to_f32(v0, x0);
    bf8_to_f32(v1, x1);
#pragma unroll
    for (int j = 0; j < 8; ++j) acc[j] = fmaf(c0, x0[j], acc[j]);
#pragma unroll
    for (int j = 0; j < 8; ++j) acc[j] = fmaf(c1, x1[j], acc[j]);
  }
  if (p < end) {
    int2 pa = pairs[p];
    int4 va = *(const int4*)&xs[(size_t)pa.x * F + f8];
    float ca = __int_as_float(pa.y);
    if (DG) ca *= dinv[pa.x];
    float xa[8];
    bf8_to_f32(va, xa);
#pragma unroll
    for (int j = 0; j < 8; ++j) acc[j] = fmaf(ca, xa[j], acc[j]);
  }

  if (BF16OUT) {
    unsigned short* out = (unsigned short*)outv;
    ushort4 o0, o1;
    o0.x = f2bf(fmaxf(acc[0], 0.f)); o0.y = f2bf(fmaxf(acc[1], 0.f));
    o0.z = f2bf(fmaxf(acc[2], 0.f)); o0.w = f2bf(fmaxf(acc[3], 0.f));
    o1.x = f2bf(fmaxf(acc[4], 0.f)); o1.y = f2bf(fmaxf(acc[5], 0.f));
    o1.z = f2bf(fmaxf(acc[6], 0.f)); o1.w = f2bf(fmaxf(acc[7], 0.f));
    *(ushort4*)&out[(size_t)g * F + f8] = o0;
    *(ushort4*)&out[(size_t)g * F + f8 + 4] = o1;
  } else {
    float* out = (float*)outv;
    *(float4*)&out[(size_t)g * F + f8] = make_float4(acc[0], acc[1], acc[2], acc[3]);
    *(float4*)&out[(size_t)g * F + f8 + 4] = make_float4(acc[4], acc[5], acc[6], acc[7]);
  }
}

// ---------------- launch ----------------
extern "C" void kernel_launch(void* const* d_in, const int* in_sizes, int n_in,
                              void* d_out, int out_size, void* d_ws, size_t ws_size,
                              hipStream_t stream) {
  const float* x  = (const float*)d_in[0];
  const int*   ei = (const int*)d_in[1];
  const float* ew = (const float*)d_in[2];
  const float* W1 = (const float*)d_in[3];
  const float* b1 = (const float*)d_in[4];
  const float* W2 = (const float*)d_in[5];
  const float* b2 = (const float*)d_in[6];
  float* out = (float*)d_out;

  const int N = in_sizes[0] / FIN;
  const int E = in_sizes[2];
  const int* src = ei;        // edge_index[0]
  const int* dst = ei + E;    // edge_index[1]

  const int NBUK = (N + BNODES - 1) >> BSH;   // 782 for N=100000
  const int M = NBUK * GB;                    // (bucket, block) count table
  const int CHUNK = (E + GB - 1) / GB;        // 6250 (<= SCAP)
  const int nbM = (M + 4095) / 4096;          // scan chunks (<=256)
  const int NG = (N + 255) / 256;             // gemm1 blocks in fused launch

  // workspace layout (16B-aligned by construction)
  float* wsf      = (float*)d_ws;
  float* dinv     = wsf;                       // N f32
  int*   rowstart = (int*)(dinv + N);          // N i32
  int*   gcntT    = rowstart + N;              // M i32 (counts -> offsets in place)
  int*   loffB    = gcntT + M;                 // GB*NBUKP i32
  int*   bsum     = loffB + GB * NBUKP;        // 256 i32
  int2*  recsA    = (int2*)(bsum + 256);       // E int2 (block-sorted chunks)
  int2*  pairs    = recsA + E;                 // E int2 (node-ordered final)
  unsigned short* xs1 = (unsigned short*)(pairs + E);    // N*HID bf16 (unscaled x@W1)
  unsigned short* out1b = xs1 + (size_t)N * HID;         // N*HID bf16 (relu'd)
  unsigned short* xs2 = xs1;                   // alias: xs1 dead after pull_agg<HID>
  unsigned short* wp2 = out1b + (size_t)N * HID;         // 2048 bf16

  // fused: edge sort + W2 pack + gemm1 (xs1 = bf16(x @ W1), dinv-free)
  k_sort_gemm<<<GB + 1 + NG, 1024, SM_BYTES, stream>>>(src, dst, ew, recsA, gcntT,
                                                       loffB, W1, W2, wp2, x, xs1,
                                                       E, CHUNK, NBUK, N);
  k_scan_sums<<<nbM, 256, 0, stream>>>(gcntT, bsum, M);
  k_scan_emit<<<nbM, 256, 0, stream>>>(gcntT, bsum, gcntT, M, nbM);  // in-place
  k_bucket<<<NBUK, 256, 0, stream>>>(recsA, gcntT, loffB, pairs, dinv, rowstart,
                                     N, E, CHUNK, NBUK);

  // layer 1 aggregate: out1b = bf16(relu(b1 + di^2*xs1[g] + sum coef*dinv[s]*xs1[s]))
  pull_agg<HID, true, true><<<(N + 31) / 32, 256, 0, stream>>>(xs1, pairs, rowstart,
                                                               dinv, b1, out1b, N, E);
  // layer 2: xs2 = bf16(dinv * (out1b @ W2));  out = pull(xs2) (fp32)
  mfma_gemm2<HID, CLS><<<(N + 63) / 64, 256, 0, stream>>>(out1b, wp2, dinv, xs2, N);
  pull_agg<CLS, false, false><<<(N + 63) / 64, 256, 0, stream>>>(xs2, pairs, rowstart,
                                                                 dinv, b2, out, N, E);
}

// Round 22
// 228.273 us; speedup vs baseline: 1.0044x; 1.0044x over previous
//
#include <hip/hip_runtime.h>

#define FIN 128
#define HID 64
#define CLS 32

#define BSH 7            // bucket covers 128 nodes
#define BNODES 128
#define GB 256           // chunks / blocks in sort pass (CHUNK=6250 @ E=1.6M)
#define BCAP 4096        // max records per bucket staged in LDS (mean ~2046)
#define SCAP 6272        // >= CHUNK: per-block staging capacity
#define NBUKP 800        // padded per-block loffB stride (>= NBUK+1)

// dynamic-LDS layout for the fused first kernel
#define SM_STAGE 0                     // int2[SCAP]   = 50176 B
#define SM_LCNT  50176                 // int[NBUKP]*3 = 9600 B
#define SM_SSUM  (50176 + 9600)       // int[1024]    = 4096 B
#define SM_BYTES (50176 + 9600 + 4096) // 63872 (gemm path reuses first 32 KB)

// R21: R18 8-deep pull_agg probe, now against a 4x-confirmed baseline
// (228.9/229.7/229.3/230.0us). Extends R0's measured 2->4 win (-5.3us).
// Single change; per-node accumulation order identical (e0->e7 sequential),
// so absmax unchanged. Revert path: quadruple-measured R17 source.

using bfrag = __attribute__((ext_vector_type(8))) short;   // 8 bf16 (4 VGPRs)
using cfrag = __attribute__((ext_vector_type(4))) float;   // 4 fp32 acc

__device__ inline unsigned short f2bf(float x) {
  unsigned u = __float_as_uint(x);
  return (unsigned short)((u + 0x7FFFu + ((u >> 16) & 1u)) >> 16);
}
__device__ inline void bf8_to_f32(int4 v, float* f) {
  f[0] = __uint_as_float((unsigned)v.x << 16);
  f[1] = __uint_as_float((unsigned)v.x & 0xFFFF0000u);
  f[2] = __uint_as_float((unsigned)v.y << 16);
  f[3] = __uint_as_float((unsigned)v.y & 0xFFFF0000u);
  f[4] = __uint_as_float((unsigned)v.z << 16);
  f[5] = __uint_as_float((unsigned)v.z & 0xFFFF0000u);
  f[6] = __uint_as_float((unsigned)v.w << 16);
  f[7] = __uint_as_float((unsigned)v.w & 0xFFFF0000u);
}

// ---------------- fused first dispatch ----------------
// blocks [0,GB):       block-local counting sort of edge chunks
// block GB:            W2 pre-pack (B-frag order)
// blocks (GB, GB+NG]:  gemm1: xs1 = bf16(x @ W1)  (UNSCALED — dinv deferred to pull)
// Sort and gemm blocks co-resident: mutual latency hiding (R16 lesson).
__global__ __launch_bounds__(1024) void k_sort_gemm(const int* __restrict__ src,
                                                    const int* __restrict__ dst,
                                                    const float* __restrict__ ew,
                                                    int2* __restrict__ recsA,
                                                    int* __restrict__ gcntT,
                                                    int* __restrict__ loffB,
                                                    const float* __restrict__ W1,
                                                    const float* __restrict__ W2,
                                                    unsigned short* __restrict__ wp2,
                                                    const float* __restrict__ x,
                                                    unsigned short* __restrict__ xs1,
                                                    int E, int CHUNK, int NBUK, int N) {
  extern __shared__ char sm[];
  const int b = blockIdx.x, t = threadIdx.x;

  if (b == GB) {  // ---- W2 pack ----
    for (int i = t; i < 4 * 512; i += 1024) {
      int f = i >> 9, l = (i >> 3) & 63, j = i & 7;
      int ks = f >> 1, nt = f & 1;
      int k = ks * 32 + (l >> 4) * 8 + j;
      int n = nt * 16 + (l & 15);
      wp2[i] = f2bf(W2[k * 32 + n]);
    }
    return;
  }

  if (b > GB) {  // ---- gemm1 blocks: 256 rows each (16 waves x 16-row tiles) ----
    float* w1s = (float*)sm;  // 32 KB
    for (int i = t; i < FIN * HID; i += 1024) w1s[i] = W1[i];
    __syncthreads();
    const int lane = t & 63;
    const int quad = lane >> 4;
    const int col = lane & 15;
    const int row0 = (b - GB - 1) * 256 + (t >> 6) * 16;
    if (row0 >= N) return;

    bfrag bf[16];
#pragma unroll
    for (int ks = 0; ks < 4; ++ks)
#pragma unroll
      for (int nt = 0; nt < 4; ++nt) {
        bfrag v;
#pragma unroll
        for (int j = 0; j < 8; ++j)
          v[j] = (short)f2bf(w1s[(ks * 32 + quad * 8 + j) * HID + nt * 16 + col]);
        bf[ks * 4 + nt] = v;
      }

    cfrag acc[4] = {};
    int row_a = row0 + col;
    if (row_a >= N) row_a = N - 1;
    const float* xp = x + (size_t)row_a * FIN + quad * 8;

#pragma unroll
    for (int ks = 0; ks < 4; ++ks) {
      float4 a0 = *(const float4*)(xp + ks * 32);
      float4 a1 = *(const float4*)(xp + ks * 32 + 4);
      bfrag af;
      af[0] = (short)f2bf(a0.x); af[1] = (short)f2bf(a0.y);
      af[2] = (short)f2bf(a0.z); af[3] = (short)f2bf(a0.w);
      af[4] = (short)f2bf(a1.x); af[5] = (short)f2bf(a1.y);
      af[6] = (short)f2bf(a1.z); af[7] = (short)f2bf(a1.w);
#pragma unroll
      for (int nt = 0; nt < 4; ++nt)
        acc[nt] = __builtin_amdgcn_mfma_f32_16x16x32_bf16(af, bf[ks * 4 + nt], acc[nt], 0, 0, 0);
    }
#pragma unroll
    for (int nt = 0; nt < 4; ++nt)
#pragma unroll
      for (int r = 0; r < 4; ++r) {
        int row = row0 + quad * 4 + r;
        if (row < N)
          xs1[(size_t)row * HID + nt * 16 + col] = f2bf(acc[nt][r]);
      }
    return;
  }

  // ---- sort blocks ----
  int2* stage = (int2*)(sm + SM_STAGE);
  int* lcnt = (int*)(sm + SM_LCNT);
  int* loff = lcnt + NBUKP;
  int* lcur = loff + NBUKP;
  int* ssum = (int*)(sm + SM_SSUM);

  const int s = b * CHUNK, e = min(E, s + CHUNK);
  const int m = e - s;

  for (int i = t; i < NBUK; i += 1024) lcnt[i] = 0;
  __syncthreads();
  for (int p = s + t; p < e; p += 1024)
    atomicAdd(&lcnt[dst[p] >> BSH], 1);
  __syncthreads();

  // R11 scan: per-wave __shfl_up + thread-0 serial scan of 16 wave totals.
  int c = (t < NBUK) ? lcnt[t] : 0;
  int incl = c;
#pragma unroll
  for (int off = 1; off < 64; off <<= 1) {
    int v = __shfl_up(incl, off, 64);
    if ((t & 63) >= off) incl += v;
  }
  if ((t & 63) == 63) ssum[t >> 6] = incl;   // 16 wave totals
  __syncthreads();
  if (t == 0) {
    int run = 0;
#pragma unroll
    for (int w = 0; w < 16; ++w) {
      int v = ssum[w];
      ssum[16 + w] = run;                    // exclusive wave offset
      run += v;
    }
  }
  __syncthreads();
  incl += ssum[16 + (t >> 6)];

  if (t < NBUK) { loff[t] = incl - c; lcur[t] = incl - c; }
  if (t == 0) loff[NBUK] = m;
  __syncthreads();

  for (int p = s + t; p < e; p += 1024) {
    int d = dst[p];
    int bk = d >> BSH;
    int pos = atomicAdd(&lcur[bk], 1);
    stage[pos] = make_int2(src[p] | ((d & (BNODES - 1)) << 17), __float_as_int(ew[p]));
  }
  __syncthreads();

  for (int p = t; p < m; p += 1024) recsA[s + p] = stage[p];
  for (int i = t; i < NBUK; i += 1024) gcntT[i * GB + b] = lcnt[i];
  for (int i = t; i <= NBUK; i += 1024) loffB[b * NBUKP + i] = loff[i];
}

// ---------------- 2-level exclusive scan (chunk = 4096, <=256 chunks) ----------------
__global__ __launch_bounds__(256) void k_scan_sums(const int* __restrict__ counts,
                                                   int* __restrict__ bsum, int N) {
  __shared__ int s[256];
  int base = blockIdx.x * 4096 + threadIdx.x * 16;
  int t = 0;
#pragma unroll
  for (int j = 0; j < 16; ++j)
    if (base + j < N) t += counts[base + j];
  s[threadIdx.x] = t;
  __syncthreads();
  for (int off = 128; off > 0; off >>= 1) {
    if (threadIdx.x < off) s[threadIdx.x] += s[threadIdx.x + off];
    __syncthreads();
  }
  if (threadIdx.x == 0) bsum[blockIdx.x] = s[0];
}

// in-place safe; each block redundantly scans bsum[0..nb) in LDS (nb <= 256)
__global__ __launch_bounds__(256) void k_scan_emit(const int* __restrict__ counts,
                                                   const int* __restrict__ bsum,
                                                   int* __restrict__ rowstart, int N, int nb) {
  __shared__ int sb[256];
  __shared__ int s[256];
  const int t = threadIdx.x;
  int bv = (t < nb) ? bsum[t] : 0;
  sb[t] = bv;
  __syncthreads();
  for (int off = 1; off < 256; off <<= 1) {
    int u = (t >= off) ? sb[t - off] : 0;
    __syncthreads();
    sb[t] += u;
    __syncthreads();
  }
  sb[t] -= bv;  // exclusive
  __syncthreads();
  const int bbase = sb[blockIdx.x];

  int base = blockIdx.x * 4096 + t * 16;
  int c[16];
  int tsum = 0;
#pragma unroll
  for (int j = 0; j < 16; ++j) {
    c[j] = (base + j < N) ? counts[base + j] : 0;
    tsum += c[j];
  }
  s[t] = tsum;
  __syncthreads();
  for (int off = 1; off < 256; off <<= 1) {
    int v = (t >= off) ? s[t - off] : 0;
    __syncthreads();
    s[t] += v;
    __syncthreads();
  }
  int run = bbase + s[t] - tsum;  // exclusive
#pragma unroll
  for (int j = 0; j < 16; ++j) {
    if (base + j < N) rowstart[base + j] = run;
    run += c[j];
  }
}

// ---------------- per-bucket finalize: node-ordered pairs via global scan ----------------
// R2 (measured -4.9us): flattened coalesced gather via run-start table +
// 8-step LDS binary search; consecutive p -> consecutive recsA addresses.
__global__ __launch_bounds__(256) void k_bucket(const int2* __restrict__ recsA,
                                                const int* __restrict__ goff,
                                                const int* __restrict__ loffB,
                                                int2* __restrict__ pairs,
                                                float* __restrict__ dinv,
                                                int* __restrict__ rowstart,
                                                int N, int E, int CHUNK, int NBUK) {
  __shared__ int2 lrec[BCAP];
  __shared__ int2 sout[BCAP];
  __shared__ int cnt[BNODES];
  __shared__ int cur[BNODES];
  __shared__ int sbuf[BNODES];
  __shared__ float degs[BNODES];
  __shared__ float dl[BNODES];
  __shared__ int rs[GB + 1];    // flattened run starts (monotone)
  __shared__ int ibase[GB];     // recsA index base per run: addr = ibase[r] + p
  const int b = blockIdx.x;
  const int t = threadIdx.x;
  const int bstart = goff[b * GB];
  const int bend = (b + 1 < NBUK) ? goff[(b + 1) * GB] : E;
  int m = bend - bstart;
  if (m > BCAP) m = BCAP;

  if (t < BNODES) { cnt[t] = 0; degs[t] = 1.0f; }  // self-loop weight
  // build run table (all 256 threads; GB == blockDim)
  {
    int ls = loffB[t * NBUKP + b];
    int doff = goff[b * GB + t] - bstart;
    rs[t] = doff;
    ibase[t] = t * CHUNK + ls - doff;
  }
  if (t == 0) rs[GB] = m;
  __syncthreads();

  // flattened gather: consecutive p -> consecutive recsA addresses within runs
  for (int p = t; p < m; p += 256) {
    int lo = 0;
#pragma unroll
    for (int step = 128; step > 0; step >>= 1) {
      int mid = lo + step;
      if (mid <= GB - 1 && rs[mid] <= p) lo = mid;
    }
    lrec[p] = recsA[ibase[lo] + p];
  }
  __syncthreads();

  for (int p = t; p < m; p += 256) {
    int2 r = lrec[p];
    int d = (r.x >> 17) & (BNODES - 1);
    atomicAdd(&cnt[d], 1);
    atomicAdd(&degs[d], __int_as_float(r.y));
  }
  __syncthreads();
  if (t < BNODES) sbuf[t] = cnt[t];
  __syncthreads();
  for (int off = 1; off < BNODES; off <<= 1) {
    int v = (t < BNODES && t >= off) ? sbuf[t - off] : 0;
    __syncthreads();
    if (t < BNODES) sbuf[t] += v;
    __syncthreads();
  }
  if (t < BNODES) {
    int ls = sbuf[t] - cnt[t];
    cur[t] = ls;
    float di = rsqrtf(degs[t]);
    dl[t] = di;
    int node = b * BNODES + t;
    if (node < N) { dinv[node] = di; rowstart[node] = bstart + ls; }
  }
  __syncthreads();
  for (int p = t; p < m; p += 256) {
    int2 r = lrec[p];
    int d = (r.x >> 17) & (BNODES - 1);
    int pos = atomicAdd(&cur[d], 1);
    float c = __int_as_float(r.y) * dl[d];  // ew * dinv[dst]
    sout[pos] = make_int2(r.x & 0x1FFFF, __float_as_int(c));
  }
  __syncthreads();
  for (int p = t; p < m; p += 256) pairs[bstart + p] = sout[p];
}

// ---------------- MFMA dense transform (layer 2): xs2 = bf16(dinv * (out1b @ W2)) ----------------
template <int K, int F>
__global__ __launch_bounds__(256, 4) void mfma_gemm2(const unsigned short* __restrict__ xv,
                                                     const unsigned short* __restrict__ wp,
                                                     const float* __restrict__ scale,
                                                     unsigned short* __restrict__ y, int N) {
  constexpr int KS = K / 32;
  constexpr int NT = F / 16;
  const int lane = threadIdx.x & 63;
  const int quad = lane >> 4;
  const int col = lane & 15;
  const int row0 = blockIdx.x * 64 + (threadIdx.x >> 6) * 16;
  if (row0 >= N) return;

  bfrag bf[KS * NT];
#pragma unroll
  for (int f = 0; f < KS * NT; ++f)
    bf[f] = *(const bfrag*)(wp + f * 512 + lane * 8);

  cfrag acc[NT] = {};
  int row_a = row0 + col;
  if (row_a >= N) row_a = N - 1;
  const unsigned short* xp = xv + (size_t)row_a * K + quad * 8;

#pragma unroll
  for (int ks = 0; ks < KS; ++ks) {
    bfrag af = *(const bfrag*)(xp + ks * 32);
#pragma unroll
    for (int nt = 0; nt < NT; ++nt)
      acc[nt] = __builtin_amdgcn_mfma_f32_16x16x32_bf16(af, bf[ks * NT + nt], acc[nt], 0, 0, 0);
  }

  float scr[4];
#pragma unroll
  for (int r = 0; r < 4; ++r) {
    int row = row0 + quad * 4 + r;
    scr[r] = (row < N) ? scale[row] : 0.f;
  }
#pragma unroll
  for (int nt = 0; nt < NT; ++nt)
#pragma unroll
    for (int r = 0; r < 4; ++r) {
      int row = row0 + quad * 4 + r;
      if (row < N)
        y[(size_t)row * F + nt * 16 + col] = f2bf(scr[r] * acc[nt][r]);
    }
}

// ---------------- pull aggregation ----------------
// DG=true  (layer 1): xs unscaled; out = b + di^2*xs[g] + sum coef*dinv[src]*xs[src]
// DG=false (layer 2): xs prescaled; out = b + di*xs[g] + sum coef*xs[src]
// R0 (measured -5.3us): 2->4 deep unroll. R21: 4->8 deep (ILP ladder probe).
template <int F, bool BF16OUT, bool DG>
__global__ __launch_bounds__(256) void pull_agg(const unsigned short* __restrict__ xs,
                                                const int2* __restrict__ pairs,
                                                const int* __restrict__ rowstart,
                                                const float* __restrict__ dinv,
                                                const float* __restrict__ b,
                                                void* __restrict__ outv, int N, int E) {
  constexpr int LPN = F / 8;        // lanes per node (8 features each, 16B loads)
  constexpr int NPB = 256 / LPN;
  const int g = blockIdx.x * NPB + threadIdx.x / LPN;
  const int f8 = (threadIdx.x % LPN) * 8;
  if (g >= N) return;

  const int start = rowstart[g];
  const int end = (g + 1 < N) ? rowstart[g + 1] : E;
  const float di = dinv[g];
  const float selfc = DG ? di * di : di;

  float acc[8];
  {
    int4 v = *(const int4*)&xs[(size_t)g * F + f8];
    float xf[8];
    bf8_to_f32(v, xf);
    float4 b0 = *(const float4*)&b[f8];
    float4 b1 = *(const float4*)&b[f8 + 4];
    acc[0] = fmaf(selfc, xf[0], b0.x); acc[1] = fmaf(selfc, xf[1], b0.y);
    acc[2] = fmaf(selfc, xf[2], b0.z); acc[3] = fmaf(selfc, xf[3], b0.w);
    acc[4] = fmaf(selfc, xf[4], b1.x); acc[5] = fmaf(selfc, xf[5], b1.y);
    acc[6] = fmaf(selfc, xf[6], b1.z); acc[7] = fmaf(selfc, xf[7], b1.w);
  }

  int p = start;
  // R21: 8-deep main loop — issue all 8 pair loads, then all 8 row gathers,
  // then convert+FMA in order (same per-edge math and accumulation order).
  for (; p + 8 <= end; p += 8) {
    int2 e0 = pairs[p];
    int2 e1 = pairs[p + 1];
    int2 e2 = pairs[p + 2];
    int2 e3 = pairs[p + 3];
    int2 e4 = pairs[p + 4];
    int2 e5 = pairs[p + 5];
    int2 e6 = pairs[p + 6];
    int2 e7 = pairs[p + 7];
    int4 v0 = *(const int4*)&xs[(size_t)e0.x * F + f8];
    int4 v1 = *(const int4*)&xs[(size_t)e1.x * F + f8];
    int4 v2 = *(const int4*)&xs[(size_t)e2.x * F + f8];
    int4 v3 = *(const int4*)&xs[(size_t)e3.x * F + f8];
    int4 v4 = *(const int4*)&xs[(size_t)e4.x * F + f8];
    int4 v5 = *(const int4*)&xs[(size_t)e5.x * F + f8];
    int4 v6 = *(const int4*)&xs[(size_t)e6.x * F + f8];
    int4 v7 = *(const int4*)&xs[(size_t)e7.x * F + f8];
    float c0 = __int_as_float(e0.y), c1 = __int_as_float(e1.y);
    float c2 = __int_as_float(e2.y), c3 = __int_as_float(e3.y);
    float c4 = __int_as_float(e4.y), c5 = __int_as_float(e5.y);
    float c6 = __int_as_float(e6.y), c7 = __int_as_float(e7.y);
    if (DG) {
      c0 *= dinv[e0.x]; c1 *= dinv[e1.x];
      c2 *= dinv[e2.x]; c3 *= dinv[e3.x];
      c4 *= dinv[e4.x]; c5 *= dinv[e5.x];
      c6 *= dinv[e6.x]; c7 *= dinv[e7.x];
    }
    float xb[8];
    bf8_to_f32(v0, xb);
#pragma unroll
    for (int j = 0; j < 8; ++j) acc[j] = fmaf(c0, xb[j], acc[j]);
    bf8_to_f32(v1, xb);
#pragma unroll
    for (int j = 0; j < 8; ++j) acc[j] = fmaf(c1, xb[j], acc[j]);
    bf8_to_f32(v2, xb);
#pragma unroll
    for (int j = 0; j < 8; ++j) acc[j] = fmaf(c2, xb[j], acc[j]);
    bf8_to_f32(v3, xb);
#pragma unroll
    for (int j = 0; j < 8; ++j) acc[j] = fmaf(c3, xb[j], acc[j]);
    bf8_to_f32(v4, xb);
#pragma unroll
    for (int j = 0; j < 8; ++j) acc[j] = fmaf(c4, xb[j], acc[j]);
    bf8_to_f32(v5, xb);
#pragma unroll
    for (int j = 0; j < 8; ++j) acc[j] = fmaf(c5, xb[j], acc[j]);
    bf8_to_f32(v6, xb);
#pragma unroll
    for (int j = 0; j < 8; ++j) acc[j] = fmaf(c6, xb[j], acc[j]);
    bf8_to_f32(v7, xb);
#pragma unroll
    for (int j = 0; j < 8; ++j) acc[j] = fmaf(c7, xb[j], acc[j]);
  }
  for (; p + 4 <= end; p += 4) {
    int2 e0 = pairs[p];
    int2 e1 = pairs[p + 1];
    int2 e2 = pairs[p + 2];
    int2 e3 = pairs[p + 3];
    int4 v0 = *(const int4*)&xs[(size_t)e0.x * F + f8];
    int4 v1 = *(const int4*)&xs[(size_t)e1.x * F + f8];
    int4 v2 = *(const int4*)&xs[(size_t)e2.x * F + f8];
    int4 v3 = *(const int4*)&xs[(size_t)e3.x * F + f8];
    float c0 = __int_as_float(e0.y), c1 = __int_as_float(e1.y);
    float c2 = __int_as_float(e2.y), c3 = __int_as_float(e3.y);
    if (DG) {
      c0 *= dinv[e0.x]; c1 *= dinv[e1.x];
      c2 *= dinv[e2.x]; c3 *= dinv[e3.x];
    }
    float x0[8], x1[8], x2[8], x3[8];
    bf8_to_f32(v0, x0);
    bf8_to_f32(v1, x1);
    bf8_to_f32(v2, x2);
    bf8_to_f32(v3, x3);
#pragma unroll
    for (int j = 0; j < 8; ++j) acc[j] = fmaf(c0, x0[j], acc[j]);
#pragma unroll
    for (int j = 0; j < 8; ++j) acc[j] = fmaf(c1, x1[j], acc[j]);
#pragma unroll
    for (int j = 0; j < 8; ++j) acc[j] = fmaf(c2, x2[j], acc[j]);
#pragma unroll
    for (int j = 0; j < 8; ++j) acc[j] = fmaf(c3, x3[j], acc[j]);
  }
  for (; p + 2 <= end; p += 2) {
    int2 p0 = pairs[p];
    int2 p1 = pairs[p + 1];
    int4 v0 = *(const int4*)&xs[(size_t)p0.x * F + f8];
    int4 v1 = *(const int4*)&xs[(size_t)p1.x * F + f8];
    float c0 = __int_as_float(p0.y), c1 = __int_as_float(p1.y);
    if (DG) { c0 *= dinv[p0.x]; c1 *= dinv[p1.x]; }
    float x0[8], x1[8];
    bf8_to_f32(v0, x0);
    bf8_to_f32(v1, x1);
#pragma unroll
    for (int j = 0; j < 8; ++j) acc[j] = fmaf(c0, x0[j], acc[j]);
#pragma unroll
    for (int j = 0; j < 8; ++j) acc[j] = fmaf(c1, x1[j], acc[j]);
  }
  if (p < end) {
    int2 pa = pairs[p];
    int4 va = *(const int4*)&xs[(size_t)pa.x * F + f8];
    float ca = __int_as_float(pa.y);
    if (DG) ca *= dinv[pa.x];
    float xa[8];
    bf8_to_f32(va, xa);
#pragma unroll
    for (int j = 0; j < 8; ++j) acc[j] = fmaf(ca, xa[j], acc[j]);
  }

  if (BF16OUT) {
    unsigned short* out = (unsigned short*)outv;
    ushort4 o0, o1;
    o0.x = f2bf(fmaxf(acc[0], 0.f)); o0.y = f2bf(fmaxf(acc[1], 0.f));
    o0.z = f2bf(fmaxf(acc[2], 0.f)); o0.w = f2bf(fmaxf(acc[3], 0.f));
    o1.x = f2bf(fmaxf(acc[4], 0.f)); o1.y = f2bf(fmaxf(acc[5], 0.f));
    o1.z = f2bf(fmaxf(acc[6], 0.f)); o1.w = f2bf(fmaxf(acc[7], 0.f));
    *(ushort4*)&out[(size_t)g * F + f8] = o0;
    *(ushort4*)&out[(size_t)g * F + f8 + 4] = o1;
  } else {
    float* out = (float*)outv;
    *(float4*)&out[(size_t)g * F + f8] = make_float4(acc[0], acc[1], acc[2], acc[3]);
    *(float4*)&out[(size_t)g * F + f8 + 4] = make_float4(acc[4], acc[5], acc[6], acc[7]);
  }
}

// ---------------- launch ----------------
extern "C" void kernel_launch(void* const* d_in, const int* in_sizes, int n_in,
                              void* d_out, int out_size, void* d_ws, size_t ws_size,
                              hipStream_t stream) {
  const float* x  = (const float*)d_in[0];
  const int*   ei = (const int*)d_in[1];
  const float* ew = (const float*)d_in[2];
  const float* W1 = (const float*)d_in[3];
  const float* b1 = (const float*)d_in[4];
  const float* W2 = (const float*)d_in[5];
  const float* b2 = (const float*)d_in[6];
  float* out = (float*)d_out;

  const int N = in_sizes[0] / FIN;
  const int E = in_sizes[2];
  const int* src = ei;        // edge_index[0]
  const int* dst = ei + E;    // edge_index[1]

  const int NBUK = (N + BNODES - 1) >> BSH;   // 782 for N=100000
  const int M = NBUK * GB;                    // (bucket, block) count table
  const int CHUNK = (E + GB - 1) / GB;        // 6250 (<= SCAP)
  const int nbM = (M + 4095) / 4096;          // scan chunks (<=256)
  const int NG = (N + 255) / 256;             // gemm1 blocks in fused launch

  // workspace layout (16B-aligned by construction)
  float* wsf      = (float*)d_ws;
  float* dinv     = wsf;                       // N f32
  int*   rowstart = (int*)(dinv + N);          // N i32
  int*   gcntT    = rowstart + N;              // M i32 (counts -> offsets in place)
  int*   loffB    = gcntT + M;                 // GB*NBUKP i32
  int*   bsum     = loffB + GB * NBUKP;        // 256 i32
  int2*  recsA    = (int2*)(bsum + 256);       // E int2 (block-sorted chunks)
  int2*  pairs    = recsA + E;                 // E int2 (node-ordered final)
  unsigned short* xs1 = (unsigned short*)(pairs + E);    // N*HID bf16 (unscaled x@W1)
  unsigned short* out1b = xs1 + (size_t)N * HID;         // N*HID bf16 (relu'd)
  unsigned short* xs2 = xs1;                   // alias: xs1 dead after pull_agg<HID>
  unsigned short* wp2 = out1b + (size_t)N * HID;         // 2048 bf16

  // fused: edge sort + W2 pack + gemm1 (xs1 = bf16(x @ W1), dinv-free)
  k_sort_gemm<<<GB + 1 + NG, 1024, SM_BYTES, stream>>>(src, dst, ew, recsA, gcntT,
                                                       loffB, W1, W2, wp2, x, xs1,
                                                       E, CHUNK, NBUK, N);
  k_scan_sums<<<nbM, 256, 0, stream>>>(gcntT, bsum, M);
  k_scan_emit<<<nbM, 256, 0, stream>>>(gcntT, bsum, gcntT, M, nbM);  // in-place
  k_bucket<<<NBUK, 256, 0, stream>>>(recsA, gcntT, loffB, pairs, dinv, rowstart,
                                     N, E, CHUNK, NBUK);

  // layer 1 aggregate: out1b = bf16(relu(b1 + di^2*xs1[g] + sum coef*dinv[s]*xs1[s]))
  pull_agg<HID, true, true><<<(N + 31) / 32, 256, 0, stream>>>(xs1, pairs, rowstart,
                                                               dinv, b1, out1b, N, E);
  // layer 2: xs2 = bf16(dinv * (out1b @ W2));  out = pull(xs2) (fp32)
  mfma_gemm2<HID, CLS><<<(N + 63) / 64, 256, 0, stream>>>(out1b, wp2, dinv, xs2, N);
  pull_agg<CLS, false, false><<<(N + 63) / 64, 256, 0, stream>>>(xs2, pairs, rowstart,
                                                                 dinv, b2, out, N, E);
}